// Round 1
// baseline (330.408 us; speedup 1.0000x reference)
//
#include <hip/hip_runtime.h>
#include <hip/hip_bf16.h>
#include <cstddef>

// Problem constants (fixed by setup_inputs)
#define T_TOK 512
#define NH    12
#define HD    64
#define NV    32000
#define CEMB  768
#define NC    50          // vocab chunks
#define VC    (NV/NC)     // 640 rows per chunk
#define NSUB  (VC/64)     // 10 subtiles of 64 rows
#define QTILE 256         // queries per block (2 q-groups cover T=512)
#define LOG2E 1.44269504088896340736f

typedef short v8bf __attribute__((ext_vector_type(8)));   // 8 bf16 = 4 VGPRs
typedef float v4f  __attribute__((ext_vector_type(4)));   // MFMA C/D

__device__ __forceinline__ unsigned short f2bf(float f) {
    unsigned u = __float_as_uint(f);
    u += 0x7fffu + ((u >> 16) & 1u);            // RNE
    return (unsigned short)(u >> 16);
}
// v_cvt_pk_bf16_f32: lo=bf16(a), hi=bf16(b), RNE — 1 instr vs ~9 for emulated pack.
// No builtin on gfx950; inline asm per T12 recipe. All values here are O(1) normals,
// so result is bit-identical to the f2bf emulation.
__device__ __forceinline__ unsigned cvtpk(float a, float b) {
    unsigned r;
    asm("v_cvt_pk_bf16_f32 %0, %1, %2" : "=v"(r) : "v"(a), "v"(b));
    return r;
}
__device__ __forceinline__ float bf2f(unsigned short u) {
    return __uint_as_float(((unsigned)u) << 16);
}
// async global->LDS, 16B/lane; LDS dst = wave-uniform base + lane*16
__device__ __forceinline__ void gld16(const void* g, void* l) {
    __builtin_amdgcn_global_load_lds(
        (const __attribute__((address_space(1))) unsigned*)g,
        (__attribute__((address_space(3))) unsigned*)l, 16, 0, 0);
}

// ---------------------------------------------------------------------------
// Kernel 1: Qb[h][t][d] (bf16) = (x . W_ffn^T + b) * LOG2E / tau  (fp32 math)
// log2e folded in so flash uses exp2 (1 v_exp, no mul).
// 4 tokens per 256-thread block (4x fewer tiny blocks than 64-thr version).
// ---------------------------------------------------------------------------
__global__ __launch_bounds__(256) void ffn_kernel(
        const float* __restrict__ x, const float* __restrict__ Wf,
        const float* __restrict__ bf, const float* __restrict__ temps,
        unsigned short* __restrict__ Qb) {
    const int h = blockIdx.y;
    const int tl = threadIdx.x >> 6, e = threadIdx.x & 63;
    const int t = blockIdx.x * 4 + tl;
    __shared__ float xs[4][HD];
    xs[tl][e] = x[t*CEMB + h*HD + e];
    __syncthreads();
    const float4* w4  = (const float4*)(Wf + (size_t)(h*HD + e)*HD);
    const float4* xs4 = (const float4*)xs[tl];
    float acc = bf[h*HD + e];
    #pragma unroll
    for (int i = 0; i < HD/4; ++i) {
        float4 a = xs4[i], b = w4[i];
        acc += a.x*b.x + a.y*b.y + a.z*b.z + a.w*b.w;
    }
    float tau = temps[h]; tau = (tau < 0.1f) ? 0.1f : tau;
    Qb[((size_t)h*T_TOK + t)*HD + e] = f2bf(acc * LOG2E / tau);
}

// ---------------------------------------------------------------------------
// Kernel 2: E (V,768) fp32  ->  ET[h][d][v] bf16 (v contiguous), per 64-v tile.
// ---------------------------------------------------------------------------
__global__ __launch_bounds__(256) void e_transpose(const float* __restrict__ E,
                                                   unsigned short* __restrict__ ET) {
    const int v0 = blockIdx.x * 64, h = blockIdx.y;
    const int tid = threadIdx.x;
    __shared__ float Ts[64*65];                 // [d][v], stride 65
    #pragma unroll
    for (int r = 0; r < 4; ++r) {
        int f = tid + 256*r, v = f >> 4, d4 = f & 15;
        float4 e4 = *(const float4*)&E[(size_t)(v0 + v)*CEMB + h*HD + d4*4];
        Ts[(d4*4+0)*65 + v] = e4.x;
        Ts[(d4*4+1)*65 + v] = e4.y;
        Ts[(d4*4+2)*65 + v] = e4.z;
        Ts[(d4*4+3)*65 + v] = e4.w;
    }
    __syncthreads();
    #pragma unroll
    for (int r = 0; r < 2; ++r) {
        int u = tid + 256*r, d = u >> 3, c16 = u & 7;
        const float* row = &Ts[d*65 + c16*8];
        uint4 w;
        w.x = cvtpk(row[0], row[1]);
        w.y = cvtpk(row[2], row[3]);
        w.z = cvtpk(row[4], row[5]);
        w.w = cvtpk(row[6], row[7]);
        *(uint4*)&ET[(size_t)(h*64 + d)*NV + v0 + c16*8] = w;
    }
}

// ---------------------------------------------------------------------------
// Kernel 3: MFMA flash, single barrier/subtile, dbuf K/E, XOR-swizzled LDS.
// LDS layout (per 64x64 bf16 tile, stride 64, no pad): 16B-group g of row r
// lives at swizzled group (g ^ (r&7)) -> all b128 fragment reads conflict-free.
// E staged by global_load_lds (prefetch to buf^1 at loop top); K (fp32 in HBM)
// prefetched to VGPRs at loop top, cvt+ds_write at loop bottom.
// ---------------------------------------------------------------------------
__global__ __launch_bounds__(256, 2) void flash_mfma(
        const unsigned short* __restrict__ Qb, const float* __restrict__ Wv,
        const unsigned short* __restrict__ ET, unsigned short* __restrict__ Npart,
        float* __restrict__ Zpart) {
    const int c = blockIdx.x, qg = blockIdx.y, h = blockIdx.z;
    const int tid  = threadIdx.x;
    const int wq   = tid >> 6;        // wave id: q range [wq*64, wq*64+64)
    const int lane = tid & 63;
    const int l15  = lane & 15, quad = lane >> 4;
    const int X    = l15 & 7;         // row-swizzle key for fragment reads

    __shared__ unsigned short Kb[2][64*64];   // K subtile  [v][d], swizzled
    __shared__ unsigned short Eb[2][64*64];   // E^T subtile [d][v], swizzled
    __shared__ unsigned short Ps[QTILE*64];   // P=exp2(S') [q][v], swizzled, wave-private rows

    const int tbase = qg*QTILE + wq*64;

    // ---- Q fragments (B-operand): lane holds Q[q=nt*16+l15][d=kb*32+quad*8..+7]
    v8bf qf[4][2];
    #pragma unroll
    for (int nt = 0; nt < 4; ++nt)
        #pragma unroll
        for (int kb = 0; kb < 2; ++kb)
            qf[nt][kb] = *(const v8bf*)&Qb[((size_t)h*T_TOK + tbase + nt*16 + l15)*HD
                                           + kb*32 + quad*8];

    v4f o[4][4];
    #pragma unroll
    for (int mt = 0; mt < 4; ++mt)
        #pragma unroll
        for (int nt = 0; nt < 4; ++nt) { v4f z = {0.f,0.f,0.f,0.f}; o[mt][nt] = z; }
    float zacc[4] = {0.f, 0.f, 0.f, 0.f};

    // ---- staging addressing (loop-invariant per lane) ----
    // K: wave stages rows kv = wq*16 + (lane>>2); 4 float4 loads, f4 = (lane&3)+4r
    const int kv = wq*16 + (lane >> 2);
    const int Xk = kv & 7;
    const float* kgl = Wv + ((size_t)h*NV + (size_t)c*VC + kv)*HD + (lane & 3)*4;
    int kwoff[4];
    #pragma unroll
    for (int r = 0; r < 4; ++r)
        kwoff[r] = kv*64 + (((((lane&3)>>1) + 2*r) ^ Xk))*8 + (lane&1)*4;
    // E: 2 DMA instr/wave: rows d = wq*16 + i*8 + (lane>>3), col-group Gv = (lane&7)^(lane>>3)
    const int Gv = (lane & 7) ^ (lane >> 3);
    const unsigned short* eg0 = ET + (size_t)(h*64 + wq*16 + (lane >> 3))*NV
                                   + (size_t)c*VC + Gv*8;
    const unsigned short* eg1 = eg0 + (size_t)8*NV;

    // ---- prologue: stage subtile 0 into buf 0 ----
    {
        gld16(eg0, &Eb[0][(wq*16)*64]);
        gld16(eg1, &Eb[0][(wq*16 + 8)*64]);
        float4 k0[4];
        #pragma unroll
        for (int r = 0; r < 4; ++r) k0[r] = *(const float4*)(kgl + r*16);
        #pragma unroll
        for (int r = 0; r < 4; ++r) {
            uint2 w = { cvtpk(k0[r].x, k0[r].y), cvtpk(k0[r].z, k0[r].w) };
            *(uint2*)&Kb[0][kwoff[r]] = w;
        }
        __syncthreads();
    }

    int nb = 1;                                  // buffer being filled
    for (int s = 0; s < NSUB; ++s) {
        const int cur = nb ^ 1;                  // buffer being computed on
        const bool pre = (s + 1 < NSUB);
        float4 kr[4];
        if (pre) {
            gld16(eg0 + (s+1)*64, &Eb[nb][(wq*16)*64]);
            gld16(eg1 + (s+1)*64, &Eb[nb][(wq*16 + 8)*64]);
            #pragma unroll
            for (int r = 0; r < 4; ++r)
                kr[r] = *(const float4*)(kgl + (size_t)(s+1)*4096 + r*16);
        }

        // ---- phase A: S'^T = K.Q^T (in log2 domain), P = exp2 ----
        v8bf kf[4][2];
        #pragma unroll
        for (int mt = 0; mt < 4; ++mt) {
            const int row = (mt*16 + l15)*64;
            kf[mt][0] = *(const v8bf*)&Kb[cur][row + ((quad     ^ X))*8];
            kf[mt][1] = *(const v8bf*)&Kb[cur][row + (((4+quad) ^ X))*8];
        }
        #pragma unroll
        for (int nt = 0; nt < 4; ++nt) {
            #pragma unroll
            for (int mt = 0; mt < 4; ++mt) {
                v4f sa = {0.f,0.f,0.f,0.f};
                sa = __builtin_amdgcn_mfma_f32_16x16x32_bf16(kf[mt][0], qf[nt][0], sa, 0, 0, 0);
                sa = __builtin_amdgcn_mfma_f32_16x16x32_bf16(kf[mt][1], qf[nt][1], sa, 0, 0, 0);
                float p0 = exp2f(sa[0]), p1 = exp2f(sa[1]);
                float p2 = exp2f(sa[2]), p3 = exp2f(sa[3]);
                zacc[nt] += (p0 + p1) + (p2 + p3);
                uint2 w = { cvtpk(p0, p1), cvtpk(p2, p3) };
                const int q = wq*64 + nt*16 + l15;
                *(uint2*)&Ps[q*64 + (((mt*2 + (quad>>1)) ^ X))*8 + (quad&1)*4] = w;
            }
        }

        // ---- phase B: O^T += E^T . P (Ps rows wave-private, no barrier) ----
        v8bf ef[4][2];
        #pragma unroll
        for (int mt = 0; mt < 4; ++mt) {
            const int row = (mt*16 + l15)*64;
            ef[mt][0] = *(const v8bf*)&Eb[cur][row + ((quad     ^ X))*8];
            ef[mt][1] = *(const v8bf*)&Eb[cur][row + (((4+quad) ^ X))*8];
        }
        #pragma unroll
        for (int nt = 0; nt < 4; ++nt) {
            const int q = wq*64 + nt*16 + l15;
            v8bf pf0 = *(const v8bf*)&Ps[q*64 + ((quad     ^ X))*8];
            v8bf pf1 = *(const v8bf*)&Ps[q*64 + (((4+quad) ^ X))*8];
            #pragma unroll
            for (int mt = 0; mt < 4; ++mt) {
                o[mt][nt] = __builtin_amdgcn_mfma_f32_16x16x32_bf16(ef[mt][0], pf0, o[mt][nt], 0, 0, 0);
                o[mt][nt] = __builtin_amdgcn_mfma_f32_16x16x32_bf16(ef[mt][1], pf1, o[mt][nt], 0, 0, 0);
            }
        }

        if (pre) {
            #pragma unroll
            for (int r = 0; r < 4; ++r) {
                uint2 w = { cvtpk(kr[r].x, kr[r].y), cvtpk(kr[r].z, kr[r].w) };
                *(uint2*)&Kb[nb][kwoff[r]] = w;
            }
            __syncthreads();      // drains prefetch issued a full compute-phase ago
        }
        nb ^= 1;
    }

    // ---- Z: reduce across quads ----
    #pragma unroll
    for (int nt = 0; nt < 4; ++nt) {
        float z = zacc[nt];
        z += __shfl_xor(z, 16, 64);
        z += __shfl_xor(z, 32, 64);
        if (quad == 0)
            Zpart[((size_t)c*T_TOK + tbase + nt*16 + l15)*NH + h] = z;
    }
    // ---- store O^T as bf16 (lane has 4 consecutive d per (mt,nt)) ----
    #pragma unroll
    for (int nt = 0; nt < 4; ++nt) {
        const int t = tbase + nt*16 + l15;
        unsigned short* np = Npart + (((size_t)c*T_TOK + t)*NH + h)*HD;
        #pragma unroll
        for (int mt = 0; mt < 4; ++mt) {
            v4f ov = o[mt][nt];
            uint2 w = { cvtpk(ov[0], ov[1]), cvtpk(ov[2], ov[3]) };
            *(uint2*)&np[mt*16 + quad*4] = w;
        }
    }
}

// ---------------------------------------------------------------------------
// Kernel 4: out[t, h*64+d] = sum_c N[c,t,h,d] / sum_c Z[c,t,h]   (4 elems/thr)
// ---------------------------------------------------------------------------
__global__ void combine_kernel(const unsigned short* __restrict__ Npart,
                               const float* __restrict__ Zpart,
                               float* __restrict__ out) {
    const int idx = (blockIdx.x*256 + threadIdx.x)*4;  // over T_TOK*CEMB, mult of 4
    const int t = idx / CEMB;
    const int rem = idx % CEMB;
    const int h = rem >> 6, d = rem & 63;
    float n0 = 0.f, n1 = 0.f, n2 = 0.f, n3 = 0.f, z = 0.f;
    #pragma unroll
    for (int c = 0; c < NC; ++c) {
        uint2 u = *(const uint2*)&Npart[(((size_t)c*T_TOK + t)*NH + h)*HD + d];
        n0 += bf2f((unsigned short)(u.x & 0xffffu));
        n1 += bf2f((unsigned short)(u.x >> 16));
        n2 += bf2f((unsigned short)(u.y & 0xffffu));
        n3 += bf2f((unsigned short)(u.y >> 16));
        z  += Zpart[((size_t)c*T_TOK + t)*NH + h];
    }
    const float rz = 1.0f / z;
    float4 o = { n0*rz, n1*rz, n2*rz, n3*rz };
    *(float4*)&out[idx] = o;
}

extern "C" void kernel_launch(void* const* d_in, const int* in_sizes, int n_in,
                              void* d_out, int out_size, void* d_ws, size_t ws_size,
                              hipStream_t stream) {
    const float* x     = (const float*)d_in[0];
    const float* Wf    = (const float*)d_in[1];
    const float* bf    = (const float*)d_in[2];
    const float* Wv    = (const float*)d_in[3];
    const float* temps = (const float*)d_in[4];
    const float* E     = (const float*)d_in[5];
    float* out = (float*)d_out;

    // workspace layout (bytes):
    //   Npart bf16: NC*512*12*64*2 = 39,321,600
    //   Zpart f32 : NC*512*12*4    =  1,228,800
    //   Qb    bf16: 12*512*64*2    =    786,432
    //   ET    bf16: 12*64*32000*2  = 49,152,000   (total ~90.5 MB)
    char* ws = (char*)d_ws;
    unsigned short* Npart = (unsigned short*)ws;
    float*          Zpart = (float*)(ws + 39321600);
    unsigned short* Qb    = (unsigned short*)(ws + 40550400);
    unsigned short* ET    = (unsigned short*)(ws + 41336832);

    e_transpose   <<<dim3(NV/64, NH),           256, 0, stream>>>(E, ET);
    ffn_kernel    <<<dim3(T_TOK/4, NH),         256, 0, stream>>>(x, Wf, bf, temps, Qb);
    flash_mfma    <<<dim3(NC, T_TOK/QTILE, NH), 256, 0, stream>>>(Qb, Wv, ET, Npart, Zpart);
    combine_kernel<<<dim3((T_TOK*CEMB)/1024),   256, 0, stream>>>(Npart, Zpart, out);
}